// Round 3
// baseline (441.715 us; speedup 1.0000x reference)
//
#include <hip/hip_runtime.h>
#include <hip/hip_bf16.h>
#include <math.h>

#define DIM 1280
#define NHEADS 16
#define HD 80
#define HDP 96            // head dim padded to 3*32 for MFMA k-steps
#define NSEG 8
#define SEGLEN 1024
#define TOTAL (NSEG*SEGLEN)   // 8192

typedef unsigned short u16;
typedef __attribute__((ext_vector_type(8))) short bf16x8;
typedef __attribute__((ext_vector_type(4))) float f32x4;

__device__ __forceinline__ u16 f2b(float f) {
    union { float f; unsigned int i; } v; v.f = f;
    unsigned int x = v.i;
    unsigned int r = x + 0x7FFFu + ((x >> 16) & 1u);   // RNE
    return (u16)(r >> 16);
}
__device__ __forceinline__ float b2f(u16 u) {
    union { unsigned int i; float f; } v; v.i = ((unsigned int)u) << 16;
    return v.f;
}
__device__ __forceinline__ void gload16(const u16* g, u16* l) {
    __builtin_amdgcn_global_load_lds(
        (const __attribute__((address_space(1))) unsigned int*)g,
        (__attribute__((address_space(3))) unsigned int*)l, 16, 0, 0);
}

// ---------------------------------------------------------------------------
// fp32 -> bf16 elementwise convert (4 per thread)
// ---------------------------------------------------------------------------
__global__ __launch_bounds__(256) void cvt_f32_bf16(const float* __restrict__ in,
                                                    u16* __restrict__ out, int n4) {
    int i = blockIdx.x * 256 + threadIdx.x;
    if (i >= n4) return;
    float4 a = ((const float4*)in)[i];
    u16 o[4] = { f2b(a.x), f2b(a.y), f2b(a.z), f2b(a.w) };
    *(ulong1*)&out[i*4] = *(ulong1*)o;
}

// ---------------------------------------------------------------------------
// Transpose + convert weights: in [K][N] fp32 -> out [N][K] bf16 (B^T layout)
// ---------------------------------------------------------------------------
__global__ __launch_bounds__(256) void cvtT_w(const float* __restrict__ in,
                                              u16* __restrict__ out, int K, int N) {
    __shared__ float t[32][33];
    const int kb = blockIdx.x * 32, nb = blockIdx.y * 32;
    const int tx = threadIdx.x & 31, ty = threadIdx.x >> 5;
    #pragma unroll
    for (int i = 0; i < 4; ++i) {
        int r = i*8 + ty;
        t[r][tx] = in[(size_t)(kb + r)*N + nb + tx];
    }
    __syncthreads();
    #pragma unroll
    for (int i = 0; i < 4; ++i) {
        int n = i*8 + ty;
        out[(size_t)(nb + n)*K + kb + tx] = f2b(t[tx][n]);
    }
}

// ---------------------------------------------------------------------------
// cos/sin table: cs[s*40+d] = {cos, sin} of rope angle
// ---------------------------------------------------------------------------
__global__ __launch_bounds__(256) void ctab_build(const float* __restrict__ rp,
                                                  float2* __restrict__ cs) {
    int i = blockIdx.x * 256 + threadIdx.x;
    if (i >= TOTAL*40) return;
    float s, c;
    sincosf(rp[i], &s, &c);
    cs[i] = make_float2(c, s);
}

// ---------------------------------------------------------------------------
// 256x256 8-phase bf16 MFMA GEMM (T2+T3+T4+T5+T1): C = A(MxK)@BT(NxK)^T + bias
// 512 thr = 8 waves (2M x 4N), BK=64, dbuf LDS 128KB, XOR chunk swizzle,
// counted staging (vmcnt(0) once per K-tile), raw barriers + setprio.
// MODE 0: fp32 row-major C.  MODE 1: bf16 scatter into q/k ([g][h][l][96])
// and v ([g][h][l][80]).
// ---------------------------------------------------------------------------
template<int MODE>
__global__ __launch_bounds__(512, 2) void gemm8p(
    const u16* __restrict__ A, const u16* __restrict__ BT,
    const float* __restrict__ bias,
    float* __restrict__ Cf, u16* __restrict__ qo, u16* __restrict__ ko,
    u16* __restrict__ vo, int M, int N, int K, int nbx)
{
    __shared__ u16 sA[2][256*64];   // 64KB (dbuf)
    __shared__ u16 sB[2][256*64];   // 64KB

    const int tid = threadIdx.x;
    const int w = tid >> 6, l = tid & 63;
    const int lq = l & 15, lg = l >> 4;
    const int wm = w >> 2, wn = w & 3;

    // XCD-aware bijective block swizzle (gridDim.x % 8 == 0)
    const int nwg = gridDim.x;
    const int q8 = nwg >> 3;
    const int id = blockIdx.x;
    const int id2 = (id & 7) * q8 + (id >> 3);
    const int bx = id2 % nbx, by = id2 / nbx;
    const int brow = by * 256, bcol = bx * 256;

    // staging: LDS linear dest, pre-swizzled global source (chunk ^= row&7)
    const int rlo  = w*8 + (l >> 3);           // row within 64-row stage chunk
    const int srcc = (l & 7) ^ ((l >> 3) & 7); // swizzled source 16B-chunk
    const size_t aBase = (size_t)(brow + rlo)*K + srcc*8;
    const size_t bBase = (size_t)(bcol + rlo)*K + srcc*8;

    // fragment read offsets (u16 units): row*64 + chunk'*8, chunk' = chunk^(lq&7)
    const int cx0 = (0 + lg) ^ (lq & 7);
    const int cx1 = (4 + lg) ^ (lq & 7);

    f32x4 acc[8][4] = {};
    const int NT = K >> 6;   // 20

    u16* cA = &sA[0][0]; u16* cB = &sB[0][0];
    u16* nA = &sA[1][0]; u16* nB = &sB[1][0];

    // prologue: stage tile 0
    #pragma unroll
    for (int ci = 0; ci < 4; ++ci) {
        gload16(A  + aBase + (size_t)(ci*64)*K, &cA[(ci*512 + w*64)*8]);
        gload16(BT + bBase + (size_t)(ci*64)*K, &cB[(ci*512 + w*64)*8]);
    }
    asm volatile("s_waitcnt vmcnt(0)" ::: "memory");
    __builtin_amdgcn_s_barrier();

    for (int t = 0; t < NT; ++t) {
        const bool pf = (t + 1 < NT);
        const int kb = (t + 1) << 6;
        bf16x8 af[4], bf[4];

        // ---- phase 0: s=0, mh=0 --------------------------------------
        if (pf) {
            gload16(A  + aBase + (size_t)(0*64)*K + kb, &nA[(0*512 + w*64)*8]);
            gload16(A  + aBase + (size_t)(2*64)*K + kb, &nA[(2*512 + w*64)*8]);
            gload16(BT + bBase + (size_t)(0*64)*K + kb, &nB[(0*512 + w*64)*8]);
        }
        #pragma unroll
        for (int n = 0; n < 4; ++n)
            bf[n] = *(const bf16x8*)&cB[(wn*64 + n*16 + lq)*64 + cx0*8];
        #pragma unroll
        for (int mi = 0; mi < 4; ++mi)
            af[mi] = *(const bf16x8*)&cA[(wm*128 + mi*16 + lq)*64 + cx0*8];
        __builtin_amdgcn_s_barrier();
        __builtin_amdgcn_s_setprio(1);
        #pragma unroll
        for (int mi = 0; mi < 4; ++mi)
            #pragma unroll
            for (int n = 0; n < 4; ++n)
                acc[mi][n] = __builtin_amdgcn_mfma_f32_16x16x32_bf16(af[mi], bf[n], acc[mi][n], 0, 0, 0);
        __builtin_amdgcn_s_setprio(0);
        __builtin_amdgcn_s_barrier();

        // ---- phase 1: s=0, mh=1 --------------------------------------
        if (pf) {
            gload16(A  + aBase + (size_t)(1*64)*K + kb, &nA[(1*512 + w*64)*8]);
            gload16(A  + aBase + (size_t)(3*64)*K + kb, &nA[(3*512 + w*64)*8]);
            gload16(BT + bBase + (size_t)(1*64)*K + kb, &nB[(1*512 + w*64)*8]);
        }
        #pragma unroll
        for (int mi = 0; mi < 4; ++mi)
            af[mi] = *(const bf16x8*)&cA[(wm*128 + 64 + mi*16 + lq)*64 + cx0*8];
        __builtin_amdgcn_s_barrier();
        __builtin_amdgcn_s_setprio(1);
        #pragma unroll
        for (int mi = 0; mi < 4; ++mi)
            #pragma unroll
            for (int n = 0; n < 4; ++n)
                acc[4+mi][n] = __builtin_amdgcn_mfma_f32_16x16x32_bf16(af[mi], bf[n], acc[4+mi][n], 0, 0, 0);
        __builtin_amdgcn_s_setprio(0);
        __builtin_amdgcn_s_barrier();

        // ---- phase 2: s=1, mh=0 --------------------------------------
        if (pf) {
            gload16(BT + bBase + (size_t)(2*64)*K + kb, &nB[(2*512 + w*64)*8]);
            gload16(BT + bBase + (size_t)(3*64)*K + kb, &nB[(3*512 + w*64)*8]);
        }
        #pragma unroll
        for (int n = 0; n < 4; ++n)
            bf[n] = *(const bf16x8*)&cB[(wn*64 + n*16 + lq)*64 + cx1*8];
        #pragma unroll
        for (int mi = 0; mi < 4; ++mi)
            af[mi] = *(const bf16x8*)&cA[(wm*128 + mi*16 + lq)*64 + cx1*8];
        __builtin_amdgcn_s_barrier();
        __builtin_amdgcn_s_setprio(1);
        #pragma unroll
        for (int mi = 0; mi < 4; ++mi)
            #pragma unroll
            for (int n = 0; n < 4; ++n)
                acc[mi][n] = __builtin_amdgcn_mfma_f32_16x16x32_bf16(af[mi], bf[n], acc[mi][n], 0, 0, 0);
        __builtin_amdgcn_s_setprio(0);
        __builtin_amdgcn_s_barrier();

        // ---- phase 3: s=1, mh=1 --------------------------------------
        #pragma unroll
        for (int mi = 0; mi < 4; ++mi)
            af[mi] = *(const bf16x8*)&cA[(wm*128 + 64 + mi*16 + lq)*64 + cx1*8];
        __builtin_amdgcn_s_barrier();
        __builtin_amdgcn_s_setprio(1);
        #pragma unroll
        for (int mi = 0; mi < 4; ++mi)
            #pragma unroll
            for (int n = 0; n < 4; ++n)
                acc[4+mi][n] = __builtin_amdgcn_mfma_f32_16x16x32_bf16(af[mi], bf[n], acc[4+mi][n], 0, 0, 0);
        __builtin_amdgcn_s_setprio(0);
        if (pf) asm volatile("s_waitcnt vmcnt(0)" ::: "memory");
        __builtin_amdgcn_s_barrier();

        u16* tA = cA; cA = nA; nA = tA;
        u16* tB = cB; cB = nB; nB = tB;
    }

    // epilogue
    #pragma unroll
    for (int mf = 0; mf < 8; ++mf) {
        #pragma unroll
        for (int n = 0; n < 4; ++n) {
            const int col = bcol + wn*64 + n*16 + lq;
            const float bv = bias[col];
            #pragma unroll
            for (int r = 0; r < 4; ++r) {
                const int row = brow + wm*128 + mf*16 + lg*4 + r;
                float val = acc[mf][n][r] + bv;
                if (MODE == 0) {
                    Cf[(size_t)row*N + col] = val;
                } else {
                    int part = col / DIM, rem = col - part*DIM;
                    int hh = rem / HD, dd = rem - hh*HD;
                    int g = row >> 10, ll = row & 1023;
                    size_t tok = (size_t)((g*NHEADS + hh)*SEGLEN + ll);
                    if      (part == 0) qo[tok*HDP + dd] = f2b(val);
                    else if (part == 1) ko[tok*HDP + dd] = f2b(val);
                    else                vo[tok*HD  + dd] = f2b(val);
                }
            }
        }
    }
}

// ---------------------------------------------------------------------------
// Vectorized RoPE in-place on bf16 q,k ([g][h][l][96]); zero-fills pads.
// One thread per (g,h,l) row; cos/sin from precomputed table (L2-resident).
// ---------------------------------------------------------------------------
__global__ __launch_bounds__(256) void rope_pad2(u16* __restrict__ qb, u16* __restrict__ kb,
                                                 const float2* __restrict__ cs)
{
    int idx = blockIdx.x * 256 + threadIdx.x;       // 131072 rows
    int l = idx & 1023, h = (idx >> 10) & 15, g = idx >> 14;
    size_t base = ((size_t)((g*NHEADS + h)*SEGLEN + l)) * HDP;
    const float2* c0 = cs + (size_t)(g*SEGLEN + l) * 40;
    #pragma unroll
    for (int p = 0; p < 5; ++p) {
        float cv[8], sv[8];
        #pragma unroll
        for (int j2 = 0; j2 < 4; ++j2) {
            float4 f = ((const float4*)(c0 + p*8))[j2];
            cv[j2*2] = f.x; sv[j2*2] = f.y; cv[j2*2+1] = f.z; sv[j2*2+1] = f.w;
        }
        bf16x8 qlo = *(const bf16x8*)&qb[base + p*8];
        bf16x8 qhi = *(const bf16x8*)&qb[base + 40 + p*8];
        bf16x8 klo = *(const bf16x8*)&kb[base + p*8];
        bf16x8 khi = *(const bf16x8*)&kb[base + 40 + p*8];
        bf16x8 qlo2, qhi2, klo2, khi2;
        #pragma unroll
        for (int j = 0; j < 8; ++j) {
            float a  = b2f((u16)qlo[j]), b  = b2f((u16)qhi[j]);
            qlo2[j] = (short)f2b(a*cv[j]  - b*sv[j]);
            qhi2[j] = (short)f2b(b*cv[j]  + a*sv[j]);
            float ka = b2f((u16)klo[j]), kb2 = b2f((u16)khi[j]);
            klo2[j] = (short)f2b(ka*cv[j] - kb2*sv[j]);
            khi2[j] = (short)f2b(kb2*cv[j] + ka*sv[j]);
        }
        *(bf16x8*)&qb[base + p*8]      = qlo2;
        *(bf16x8*)&qb[base + 40 + p*8] = qhi2;
        *(bf16x8*)&kb[base + p*8]      = klo2;
        *(bf16x8*)&kb[base + 40 + p*8] = khi2;
    }
    bf16x8 z = {};
    *(bf16x8*)&qb[base + 80] = z; *(bf16x8*)&qb[base + 88] = z;
    *(bf16x8*)&kb[base + 80] = z; *(bf16x8*)&kb[base + 88] = z;
}

// ---------------------------------------------------------------------------
// V transpose per head: v [gh][1024][80] -> vt [gh][80][1024]  (bf16)
// ---------------------------------------------------------------------------
__global__ __launch_bounds__(256) void transpose_v(const u16* __restrict__ v,
                                                   u16* __restrict__ vt)
{
    __shared__ u16 sT[64][82];
    const int gh = blockIdx.y;
    const int st = blockIdx.x;
    const u16* src = v  + (size_t)gh*SEGLEN*HD + (size_t)st*64*HD;
    u16*       dst = vt + (size_t)gh*HD*SEGLEN + (size_t)st*64;
    const int tid = threadIdx.x;
    #pragma unroll
    for (int p = 0; p < 20; ++p) {
        int e = p*256 + tid;
        int r = e / 80, c = e - r*80;
        sT[r][c] = src[r*HD + c];
    }
    __syncthreads();
    #pragma unroll
    for (int p = 0; p < 20; ++p) {
        int e = p*256 + tid;
        int dd = e >> 6, s = e & 63;
        dst[(size_t)dd*SEGLEN + s] = sT[s][dd];
    }
}

// ---------------------------------------------------------------------------
// Flash attention, bf16 MFMA, fp32 online softmax (unchanged from R2, passed)
// ---------------------------------------------------------------------------
__global__ __launch_bounds__(256) void attn_mfma(
    const u16* __restrict__ qb, const u16* __restrict__ kb,
    const u16* __restrict__ vt, u16* __restrict__ ob)
{
    const int qt = blockIdx.x;
    const int h  = blockIdx.y;
    const int g  = blockIdx.z;
    const float scale = 0.11180339887498949f;
    const float L2E = 1.4426950408889634f;

    __shared__ u16 sK[64*HDP];
    __shared__ u16 sVT[80][72];
    __shared__ u16 sP[4][16][72];

    const int tid = threadIdx.x;
    const int w = tid >> 6, l = tid & 63;
    const int lq = l & 15, lg = l >> 4;

    const size_t gh = (size_t)(g*NHEADS + h);
    const u16* Qg  = qb + gh*SEGLEN*HDP + (size_t)qt*64*HDP;
    const u16* Kg  = kb + gh*SEGLEN*HDP;
    const u16* VTg = vt + gh*HD*SEGLEN;

    bf16x8 qf[3];
    #pragma unroll
    for (int s = 0; s < 3; ++s)
        qf[s] = *(const bf16x8*)(Qg + (size_t)(w*16 + lq)*HDP + s*32 + lg*8);

    float m = -1e30f, lse = 0.f;
    f32x4 Oc[5] = {};

    for (int kt = 0; kt < 16; ++kt) {
        __syncthreads();
        #pragma unroll
        for (int i = 0; i < 3; ++i) {
            int o = (i*4 + w)*1024 + l*16;
            int row = o / 192, cc = (o % 192) >> 1;
            gload16(Kg + (size_t)(kt*64 + row)*HDP + cc, &sK[(i*4 + w)*512]);
        }
        #pragma unroll
        for (int p = 0; p < 3; ++p) {
            int c = p*256 + tid;
            if (c < 640) {
                int dd = c >> 3, s8 = (c & 7)*8;
                *(bf16x8*)&sVT[dd][s8] =
                    *(const bf16x8*)(VTg + (size_t)dd*SEGLEN + kt*64 + s8);
            }
        }
        __syncthreads();

        f32x4 sf[4];
        #pragma unroll
        for (int fi = 0; fi < 4; ++fi) {
            f32x4 c = {0.f, 0.f, 0.f, 0.f};
            #pragma unroll
            for (int s = 0; s < 3; ++s) {
                bf16x8 a = *(const bf16x8*)&sK[(fi*16 + lq)*HDP + s*32 + lg*8];
                c = __builtin_amdgcn_mfma_f32_16x16x32_bf16(a, qf[s], c, 0, 0, 0);
            }
            sf[fi] = c;
        }

        float sv[4][4];
        float rm = -1e30f;
        #pragma unroll
        for (int fi = 0; fi < 4; ++fi)
            #pragma unroll
            for (int r = 0; r < 4; ++r) {
                float x = sf[fi][r] * scale;
                sv[fi][r] = x;
                rm = fmaxf(rm, x);
            }
        rm = fmaxf(rm, __shfl_xor(rm, 16, 64));
        rm = fmaxf(rm, __shfl_xor(rm, 32, 64));
        float mnew = fmaxf(m, rm);
        float alpha = exp2f((m - mnew) * L2E);
        float psum = 0.f;
        #pragma unroll
        for (int fi = 0; fi < 4; ++fi)
            #pragma unroll
            for (int r = 0; r < 4; ++r) {
                float p = exp2f((sv[fi][r] - mnew) * L2E);
                sv[fi][r] = p;
                psum += p;
            }
        psum += __shfl_xor(psum, 16, 64);
        psum += __shfl_xor(psum, 32, 64);
        lse = lse * alpha + psum;
        m = mnew;

        #pragma unroll
        for (int fi = 0; fi < 4; ++fi) {
            unsigned int w0 = (unsigned int)f2b(sv[fi][0]) | ((unsigned int)f2b(sv[fi][1]) << 16);
            unsigned int w1 = (unsigned int)f2b(sv[fi][2]) | ((unsigned int)f2b(sv[fi][3]) << 16);
            uint2 val; val.x = w0; val.y = w1;
            *(uint2*)&sP[w][lq][fi*16 + lg*4] = val;
        }

        float a0 = __shfl(alpha, lg*4 + 0, 64);
        float a1 = __shfl(alpha, lg*4 + 1, 64);
        float a2 = __shfl(alpha, lg*4 + 2, 64);
        float a3 = __shfl(alpha, lg*4 + 3, 64);
        #pragma unroll
        for (int n = 0; n < 5; ++n) {
            Oc[n][0] *= a0; Oc[n][1] *= a1; Oc[n][2] *= a2; Oc[n][3] *= a3;
        }

        #pragma unroll
        for (int ks = 0; ks < 2; ++ks) {
            bf16x8 pa = *(const bf16x8*)&sP[w][lq][ks*32 + lg*8];
            #pragma unroll
            for (int n = 0; n < 5; ++n) {
                bf16x8 vb = *(const bf16x8*)&sVT[n*16 + lq][ks*32 + lg*8];
                Oc[n] = __builtin_amdgcn_mfma_f32_16x16x32_bf16(pa, vb, Oc[n], 0, 0, 0);
            }
        }
    }

    float inv = 1.f / lse;
    float i0 = __shfl(inv, lg*4 + 0, 64);
    float i1 = __shfl(inv, lg*4 + 1, 64);
    float i2 = __shfl(inv, lg*4 + 2, 64);
    float i3 = __shfl(inv, lg*4 + 3, 64);
    const float iv[4] = { i0, i1, i2, i3 };
    #pragma unroll
    for (int n = 0; n < 5; ++n) {
        #pragma unroll
        for (int r = 0; r < 4; ++r) {
            int tok = g*SEGLEN + qt*64 + w*16 + lg*4 + r;
            int col = h*HD + n*16 + lq;
            ob[(size_t)tok*DIM + col] = f2b(Oc[n][r] * iv[r]);
        }
    }
}

// ---------------------------------------------------------------------------
extern "C" void kernel_launch(void* const* d_in, const int* in_sizes, int n_in,
                              void* d_out, int out_size, void* d_ws, size_t ws_size,
                              hipStream_t stream) {
    const float* hs     = (const float*)d_in[0];
    const float* rope   = (const float*)d_in[1];
    const float* qkv_w  = (const float*)d_in[2];
    const float* qkv_b  = (const float*)d_in[3];
    const float* proj_w = (const float*)d_in[4];
    const float* proj_b = (const float*)d_in[5];

    char* ws = (char*)d_ws;
    u16* hsb    = (u16*)(ws);                 // 8192x1280 bf16   (20,971,520 B)
    u16* wqkvt  = (u16*)(ws + 20971520);      // 3840x1280        ( 9,830,400 B)
    u16* wprojt = (u16*)(ws + 30801920);      // 1280x1280        ( 3,276,800 B)
    u16* qpad   = (u16*)(ws + 34078720);      // 128x1024x96      (25,165,824 B)
    u16* kpad   = (u16*)(ws + 59244544);      // 128x1024x96      (25,165,824 B)
    u16* vbuf   = (u16*)(ws + 84410368);      // 128x1024x80      (20,971,520 B)
    u16* vtb    = (u16*)(ws + 105381888);     // 128x80x1024      (20,971,520 B)
    u16* obb    = (u16*)(ws + 126353408);     // 8192x1280        (20,971,520 B)
    // ctab aliases obb: ctab dead (after rope) before obb is written (attn)
    float2* ctab = (float2*)(ws + 126353408); // 8192x40 float2   ( 2,621,440 B)

    // 1. converts + rope table
    cvt_f32_bf16<<<(TOTAL*DIM/4 + 255)/256, 256, 0, stream>>>(hs, hsb, TOTAL*DIM/4);
    cvtT_w<<<dim3(DIM/32, 3*DIM/32), 256, 0, stream>>>(qkv_w, wqkvt, DIM, 3*DIM);
    cvtT_w<<<dim3(DIM/32, DIM/32), 256, 0, stream>>>(proj_w, wprojt, DIM, DIM);
    ctab_build<<<(TOTAL*40 + 255)/256, 256, 0, stream>>>(rope, ctab);

    // 2. QKV GEMM (8-phase) + scatter:  grid 15x32 = 480 blocks
    gemm8p<1><<<dim3((3*DIM/256) * (TOTAL/256)), 512, 0, stream>>>(
        hsb, wqkvt, qkv_b, nullptr, qpad, kpad, vbuf, TOTAL, 3*DIM, DIM, 3*DIM/256);

    // 3. RoPE + pad zero-fill (vectorized)
    rope_pad2<<<NSEG*NHEADS*SEGLEN/256, 256, 0, stream>>>(qpad, kpad, ctab);

    // 4. V transpose
    transpose_v<<<dim3(SEGLEN/64, NSEG*NHEADS), 256, 0, stream>>>(vbuf, vtb);

    // 5. flash attention
    attn_mfma<<<dim3(SEGLEN/64, NHEADS, NSEG), 256, 0, stream>>>(qpad, kpad, vtb, obb);

    // 6. output projection (8-phase): grid 5x32 = 160 blocks
    gemm8p<0><<<dim3((DIM/256) * (TOTAL/256)), 512, 0, stream>>>(
        obb, wprojt, proj_b, (float*)d_out, nullptr, nullptr, nullptr, TOTAL, DIM, DIM, DIM/256);
}